// Round 2
// baseline (630.544 us; speedup 1.0000x reference)
//
#include <hip/hip_runtime.h>
#include <cstddef>

// CubicFilter: conv(s2)+lrelu -> pool -> x4 ... -> mean -> FC -> R(8,640)
// out = feat + sum_k R[b,c,k] * basis_k(h,w), basis analytic in
//   a = x_h^(255-w), b = x_w^(255-h), x_i = (i+1)/256.
// All fp32. Threshold 0.14 absolute; our errors ~1e-4.

#define LEAKY 0.01f

// ---------- weight transpose: (64,64,3,3) -> [ci*9+t][co] ----------
__global__ __launch_bounds__(256) void wtrans_k(const float* __restrict__ w,
                                                float* __restrict__ wt) {
    int idx = blockIdx.x * 256 + threadIdx.x;   // 36864 = 144*256 exact
    int co  = idx / 576;
    int rem = idx - co * 576;                   // ci*9 + t
    wt[rem * 64 + co] = w[idx];
}

// ---------- conv 3x3 stride2 pad1 + bias + LeakyReLU ----------
// wave = (b, oh, ow-chunk of PX); lane = co. Input loads are wave-uniform
// (HW broadcast); weight loads coalesced via transposed layout.
template<int IH, int IW, int OH, int OW, int PX>
__global__ __launch_bounds__(256) void conv_s2(const float* __restrict__ in,
                                               const float* __restrict__ wt,
                                               const float* __restrict__ bias,
                                               float* __restrict__ out) {
    constexpr int CI = 64, CO = 64;
    constexpr int CHUNKS = OW / PX;
    int wid  = (blockIdx.x * 256 + threadIdx.x) >> 6;
    int lane = threadIdx.x & 63;
    int chunk = wid % CHUNKS;
    int t     = wid / CHUNKS;
    int oh    = t % OH;
    int b     = t / OH;
    int ow0   = chunk * PX;

    float acc[PX];
#pragma unroll
    for (int p = 0; p < PX; ++p) acc[p] = 0.f;

    int r0 = 2 * oh - 1;
    for (int ci = 0; ci < CI; ++ci) {
        const float* wp = wt + ci * 9 * CO + lane;
        float wv[9];
#pragma unroll
        for (int k = 0; k < 9; ++k) wv[k] = wp[k * CO];

        const float* inb = in + ((size_t)(b * CI + ci)) * IH * IW;
#pragma unroll
        for (int dr = 0; dr < 3; ++dr) {
            int r = r0 + dr;
            if (r < 0 || r >= IH) continue;     // only oh==0,dr==0 in practice
            const float* rowp = inb + (size_t)r * IW;
            float w0 = wv[dr * 3 + 0], w1 = wv[dr * 3 + 1], w2 = wv[dr * 3 + 2];
            float left = (ow0 == 0) ? 0.f : rowp[2 * ow0 - 1];
#pragma unroll
            for (int p = 0; p < PX; p += 2) {
                float4 q = *reinterpret_cast<const float4*>(rowp + 2 * (ow0 + p));
                acc[p]     += left * w0 + q.x * w1 + q.y * w2;
                acc[p + 1] += q.y  * w0 + q.z * w1 + q.w * w2;
                left = q.w;
            }
        }
    }

    float bv = bias[lane];
    size_t obase = ((size_t)(b * CO + lane) * OH + oh) * OW + ow0;
#pragma unroll
    for (int p = 0; p < PX; ++p) {
        float v = acc[p] + bv;
        out[obase + p] = v > 0.f ? v : LEAKY * v;
    }
}

// ---------- 2x2 max pool stride 2 ----------
template<int OH, int OW>
__global__ __launch_bounds__(256) void maxpool_k(const float* __restrict__ in,
                                                 float* __restrict__ out, int total) {
    int idx = blockIdx.x * 256 + threadIdx.x;
    if (idx >= total) return;
    int x  = idx % OW;
    int t  = idx / OW;
    int y  = t % OH;
    int bc = t / OH;
    const float* p = in + ((size_t)bc * (2 * OH) + 2 * y) * (2 * OW) + 2 * x;
    float2 a = *reinterpret_cast<const float2*>(p);
    float2 b = *reinterpret_cast<const float2*>(p + 2 * OW);
    out[idx] = fmaxf(fmaxf(a.x, a.y), fmaxf(b.x, b.y));
}

// ---------- mean(2x2) + FC: R = x @ fc_w.T + fc_b ----------
__global__ __launch_bounds__(256) void meanfc_k(const float* __restrict__ in4,
                                                const float* __restrict__ fcw,
                                                const float* __restrict__ fcb,
                                                float* __restrict__ R) {
    __shared__ float xs[512];                  // (8,64)
    int tid = threadIdx.x;
    for (int i = tid; i < 512; i += 256) {
        const float* p = in4 + i * 4;
        xs[i] = 0.25f * (p[0] + p[1] + p[2] + p[3]);
    }
    __syncthreads();
    for (int o = tid; o < 8 * 640; o += 256) {
        int i = o % 640;
        int b = o / 640;
        float s = fcb[i];
        const float* wrow = fcw + i * 64;
        const float* xb   = xs + b * 64;
#pragma unroll 8
        for (int c = 0; c < 64; ++c) s += xb[c] * wrow[c];
        R[o] = s;
    }
}

// ---------- out = feat + sum_k R_k * basis_k(h,w), basis analytic ----------
// block = (b, c, h-half); thread = w. R held in 10 regs (uniform broadcast).
__global__ __launch_bounds__(256) void final_add_k(const float* __restrict__ feat,
                                                   const float* __restrict__ R,
                                                   float* __restrict__ out) {
    int blk   = blockIdx.x;
    int hhalf = blk & 1;
    int t     = blk >> 1;
    int c     = t & 63;
    int b     = t >> 6;
    int w     = threadIdx.x;

    const float* Rp = R + (b * 640 + c * 10);
    float r0 = Rp[0], r1 = Rp[1], r2 = Rp[2], r3 = Rp[3], r4 = Rp[4];
    float r5 = Rp[5], r6 = Rp[6], r7 = Rp[7], r8 = Rp[8], r9 = Rp[9];

    float xw  = (float)(w + 1) * (1.0f / 256.0f);
    float Lw  = __builtin_amdgcn_logf(xw);       // log2(x_w)  (v_log_f32)
    float ejw = (float)(255 - w);                // exponent for a

    size_t base = (((size_t)(b * 64 + c) * 256) + (size_t)hhalf * 128) * 256 + w;
    const float* fp = feat + base;
    float*       op = out + base;

#pragma unroll 4
    for (int hh = 0; hh < 128; ++hh) {
        int h = hhalf * 128 + hh;
        float xi = (float)(h + 1) * (1.0f / 256.0f);
        float Lh = __builtin_amdgcn_logf(xi);                      // log2(x_h)
        float a  = __builtin_amdgcn_exp2f(ejw * Lh);               // x_h^(255-w)
        float bb = __builtin_amdgcn_exp2f((float)(255 - h) * Lw);  // x_w^(255-h)
        float mask = (r9 + r3)
                   + bb * (r8 + bb * (r7 + bb * r6))
                   + a * ((r5 + bb * (r4 + bb * r3))
                          + a * (r2 + bb * r1 + a * r0));
        op[(size_t)hh * 256] = fp[(size_t)hh * 256] + mask;
    }
}

extern "C" void kernel_launch(void* const* d_in, const int* in_sizes, int n_in,
                              void* d_out, int out_size, void* d_ws, size_t ws_size,
                              hipStream_t stream) {
    const float* feat = (const float*)d_in[0];
    const float* w1   = (const float*)d_in[1];
    const float* b1   = (const float*)d_in[2];
    const float* w2   = (const float*)d_in[3];
    const float* b2   = (const float*)d_in[4];
    const float* w3   = (const float*)d_in[5];
    const float* b3   = (const float*)d_in[6];
    const float* w4   = (const float*)d_in[7];
    const float* b4   = (const float*)d_in[8];
    const float* fcw  = (const float*)d_in[9];
    const float* fcb  = (const float*)d_in[10];
    float* out = (float*)d_out;

    // workspace layout (floats)
    float* ws   = (float*)d_ws;
    float* wt1   = ws;            // 36864
    float* wt2   = wt1 + 36864;
    float* wt3   = wt2 + 36864;
    float* wt4   = wt3 + 36864;
    float* out1  = wt4 + 36864;   // 8*64*128*128 = 8388608
    float* pool1 = out1 + 8388608;  // 2097152
    float* out2  = pool1 + 2097152; // 524288
    float* pool2 = out2 + 524288;   // 131072
    float* out3  = pool2 + 131072;  // 32768
    float* pool3 = out3 + 32768;    // 8192
    float* out4  = pool3 + 8192;    // 2048
    float* Rm    = out4 + 2048;     // 5120

    // weight transposes (each 36864 elems = 144 blocks)
    wtrans_k<<<144, 256, 0, stream>>>(w1, wt1);
    wtrans_k<<<144, 256, 0, stream>>>(w2, wt2);
    wtrans_k<<<144, 256, 0, stream>>>(w3, wt3);
    wtrans_k<<<144, 256, 0, stream>>>(w4, wt4);

    // conv1: 256 -> 128, waves = 8*128*4 = 4096 -> 1024 blocks
    conv_s2<256, 256, 128, 128, 32><<<1024, 256, 0, stream>>>(feat, wt1, b1, out1);
    // pool1: 128 -> 64
    maxpool_k<64, 64><<<(2097152 + 255) / 256, 256, 0, stream>>>(out1, pool1, 2097152);
    // conv2: 64 -> 32, waves = 8*32*4 = 1024 -> 256 blocks
    conv_s2<64, 64, 32, 32, 8><<<256, 256, 0, stream>>>(pool1, wt2, b2, out2);
    // pool2: 32 -> 16
    maxpool_k<16, 16><<<(131072 + 255) / 256, 256, 0, stream>>>(out2, pool2, 131072);
    // conv3: 16 -> 8, waves = 8*8 = 64 -> 16 blocks
    conv_s2<16, 16, 8, 8, 8><<<16, 256, 0, stream>>>(pool2, wt3, b3, out3);
    // pool3: 8 -> 4
    maxpool_k<4, 4><<<(8192 + 255) / 256, 256, 0, stream>>>(out3, pool3, 8192);
    // conv4: 4 -> 2, waves = 8*2 = 16 -> 4 blocks
    conv_s2<4, 4, 2, 2, 2><<<4, 256, 0, stream>>>(pool3, wt4, b4, out4);
    // mean + FC
    meanfc_k<<<1, 256, 0, stream>>>(out4, fcw, fcb, Rm);
    // final: feat + mask, 8*64*2 = 1024 blocks
    final_add_k<<<1024, 256, 0, stream>>>(feat, Rm, out);
}

// Round 3
// 347.374 us; speedup vs baseline: 1.8152x; 1.8152x over previous
//
#include <hip/hip_runtime.h>
#include <hip/hip_bf16.h>
#include <cstddef>

#define LEAKY 0.01f

typedef short short8 __attribute__((ext_vector_type(8)));
typedef float f32x4 __attribute__((ext_vector_type(4)));

__device__ inline unsigned short bf16b(float f) {
    __hip_bfloat16 h = __float2bfloat16(f);   // RN
    return __builtin_bit_cast(unsigned short, h);
}

// ---------- weight transpose: (64,64,3,3) -> [ci*9+t][co] (for VALU convs 2-4) ----------
__global__ __launch_bounds__(256) void wtrans_k(const float* __restrict__ w,
                                                float* __restrict__ wt) {
    int idx = blockIdx.x * 256 + threadIdx.x;   // 36864 = 144*256 exact
    int co  = idx / 576;
    int rem = idx - co * 576;                   // ci*9 + t
    wt[rem * 64 + co] = w[idx];
}

// ---------- prepack w1 into MFMA B-fragment order ----------
// wpk[((tap*4+ct)*2+ks)*64 + lane][j] bf16, j=0..7
// B[k][n]: n = ct*16 + (lane&15), k = ks*32 + (lane>>4)*8 + j  (k = ci)
__global__ __launch_bounds__(256) void wpack_k(const float* __restrict__ w,
                                               unsigned short* __restrict__ wpk) {
    int idx = blockIdx.x * 256 + threadIdx.x;   // 36864 = 9*4*2*64*8
    int j    = idx & 7;
    int lane = (idx >> 3) & 63;
    int rest = idx >> 9;        // (tap*4+ct)*2+ks, 72 values
    int ks   = rest & 1;
    int ct   = (rest >> 1) & 3;
    int tap  = rest >> 3;       // 0..8
    int n = ct * 16 + (lane & 15);
    int k = ks * 32 + (lane >> 4) * 8 + j;
    wpk[idx] = bf16b(w[(n * 64 + k) * 9 + tap]);
}

// ---------- conv1 via MFMA: 3x3 s2 p1, 64ci->64co, 256->128, bf16 ----------
// block = (b, oh). LDS As[slot][64ci] bf16, slot = input_col+1 (slot 0 = zero pad),
// 16B ci-groups XOR-swizzled by ((slot>>1)&7) for conflict-free write AND read.
__global__ __launch_bounds__(256, 4) void conv1_mfma(const float* __restrict__ feat,
                                                     const unsigned short* __restrict__ wpk,
                                                     const float* __restrict__ bias,
                                                     float* __restrict__ out) {
    __shared__ alignas(16) unsigned short As[257 * 64];   // 32896 B

    // XCD-bijective swizzle: consecutive work-ids (adjacent oh, same b) on same XCD
    int blk  = blockIdx.x;
    int wgid = (blk & 7) * 128 + (blk >> 3);   // 1024 % 8 == 0 -> bijective
    int oh = wgid & 127;
    int b  = wgid >> 7;

    int tid  = threadIdx.x;
    int lane = tid & 63;
    int wv   = tid >> 6;        // wave 0..3, owns ow range wv*32..wv*32+31

    if (tid < 32) ((unsigned int*)As)[tid] = 0;   // zero slot 0 (128 B)

    f32x4 acc[2][4] = {};       // [mt][ct]

    int col   = tid;            // staging column 0..255
    int slotw = col + 1;
    int sW    = (slotw >> 1) & 7;
    const float* fb = feat + (size_t)b * 64 * 65536 + col;
    int kg = lane >> 4;
    int m  = lane & 15;

    for (int dr = 0; dr < 3; ++dr) {
        int r = 2 * oh - 1 + dr;
        if (r < 0) continue;                     // uniform across block
        __syncthreads();                         // previous taps done reading As
        // ---- stage row r: thread gathers 8 ci per group -> one b128 write ----
        const float* fr = fb + (size_t)r * 256;
        for (int g = 0; g < 8; ++g) {
            float v[8];
#pragma unroll
            for (int j = 0; j < 8; ++j) v[j] = fr[(size_t)(g * 8 + j) * 65536];
            short8 hv;
#pragma unroll
            for (int j = 0; j < 8; ++j) hv[j] = (short)bf16b(v[j]);
            *(short8*)(As + slotw * 64 + ((g ^ sW) << 3)) = hv;
        }
        __syncthreads();
        // ---- 3 dc-taps over this row ----
        for (int dc = 0; dc < 3; ++dc) {
            int tap = dr * 3 + dc;
            short8 Bf[4][2];
#pragma unroll
            for (int ct = 0; ct < 4; ++ct)
#pragma unroll
                for (int ks = 0; ks < 2; ++ks)
                    Bf[ct][ks] = *(const short8*)(wpk +
                        ((((tap * 4 + ct) * 2 + ks) * 64 + lane) << 3));
#pragma unroll
            for (int mt = 0; mt < 2; ++mt) {
                int c0 = 2 * (wv * 32 + mt * 16 + m) + dc;   // slot, <= 256
                int s  = (c0 >> 1) & 7;
#pragma unroll
                for (int ks = 0; ks < 2; ++ks) {
                    short8 Af = *(const short8*)(As + c0 * 64 +
                                                 (((ks * 4 + kg) ^ s) << 3));
#pragma unroll
                    for (int ct = 0; ct < 4; ++ct)
                        acc[mt][ct] = __builtin_amdgcn_mfma_f32_16x16x32_bf16(
                            Af, Bf[ct][ks], acc[mt][ct], 0, 0, 0);
                }
            }
        }
    }

    // ---- epilogue: bias + leaky, float4 stores ----
    // D: co = ct*16 + (lane&15), pixel = (lane>>4)*4 + reg
#pragma unroll
    for (int ct = 0; ct < 4; ++ct) {
        int co = ct * 16 + m;
        float bv = bias[co];
#pragma unroll
        for (int mt = 0; mt < 2; ++mt) {
            int ow = wv * 32 + mt * 16 + kg * 4;
            float4 o;
            float t0 = acc[mt][ct][0] + bv; o.x = t0 > 0.f ? t0 : LEAKY * t0;
            float t1 = acc[mt][ct][1] + bv; o.y = t1 > 0.f ? t1 : LEAKY * t1;
            float t2 = acc[mt][ct][2] + bv; o.z = t2 > 0.f ? t2 : LEAKY * t2;
            float t3 = acc[mt][ct][3] + bv; o.w = t3 > 0.f ? t3 : LEAKY * t3;
            *(float4*)(out + ((size_t)(b * 64 + co) * 128 + oh) * 128 + ow) = o;
        }
    }
}

// ---------- conv 3x3 stride2 pad1 + bias + LeakyReLU (VALU, convs 2-4) ----------
template<int IH, int IW, int OH, int OW, int PX>
__global__ __launch_bounds__(256) void conv_s2(const float* __restrict__ in,
                                               const float* __restrict__ wt,
                                               const float* __restrict__ bias,
                                               float* __restrict__ out) {
    constexpr int CI = 64, CO = 64;
    constexpr int CHUNKS = OW / PX;
    int wid  = (blockIdx.x * 256 + threadIdx.x) >> 6;
    int lane = threadIdx.x & 63;
    int chunk = wid % CHUNKS;
    int t     = wid / CHUNKS;
    int oh    = t % OH;
    int b     = t / OH;
    int ow0   = chunk * PX;

    float acc[PX];
#pragma unroll
    for (int p = 0; p < PX; ++p) acc[p] = 0.f;

    int r0 = 2 * oh - 1;
    for (int ci = 0; ci < CI; ++ci) {
        const float* wp = wt + ci * 9 * CO + lane;
        float wvv[9];
#pragma unroll
        for (int k = 0; k < 9; ++k) wvv[k] = wp[k * CO];

        const float* inb = in + ((size_t)(b * CI + ci)) * IH * IW;
#pragma unroll
        for (int dr = 0; dr < 3; ++dr) {
            int r = r0 + dr;
            if (r < 0 || r >= IH) continue;
            const float* rowp = inb + (size_t)r * IW;
            float w0 = wvv[dr * 3 + 0], w1 = wvv[dr * 3 + 1], w2 = wvv[dr * 3 + 2];
            float left = (ow0 == 0) ? 0.f : rowp[2 * ow0 - 1];
#pragma unroll
            for (int p = 0; p < PX; p += 2) {
                float4 q = *reinterpret_cast<const float4*>(rowp + 2 * (ow0 + p));
                acc[p]     += left * w0 + q.x * w1 + q.y * w2;
                acc[p + 1] += q.y  * w0 + q.z * w1 + q.w * w2;
                left = q.w;
            }
        }
    }

    float bv = bias[lane];
    size_t obase = ((size_t)(b * CO + lane) * OH + oh) * OW + ow0;
#pragma unroll
    for (int p = 0; p < PX; ++p) {
        float v = acc[p] + bv;
        out[obase + p] = v > 0.f ? v : LEAKY * v;
    }
}

// ---------- 2x2 max pool stride 2 ----------
template<int OH, int OW>
__global__ __launch_bounds__(256) void maxpool_k(const float* __restrict__ in,
                                                 float* __restrict__ out, int total) {
    int idx = blockIdx.x * 256 + threadIdx.x;
    if (idx >= total) return;
    int x  = idx % OW;
    int t  = idx / OW;
    int y  = t % OH;
    int bc = t / OH;
    const float* p = in + ((size_t)bc * (2 * OH) + 2 * y) * (2 * OW) + 2 * x;
    float2 a = *reinterpret_cast<const float2*>(p);
    float2 b = *reinterpret_cast<const float2*>(p + 2 * OW);
    out[idx] = fmaxf(fmaxf(a.x, a.y), fmaxf(b.x, b.y));
}

// ---------- mean(2x2) + FC: R = x @ fc_w.T + fc_b ----------
__global__ __launch_bounds__(256) void meanfc_k(const float* __restrict__ in4,
                                                const float* __restrict__ fcw,
                                                const float* __restrict__ fcb,
                                                float* __restrict__ R) {
    __shared__ float xs[512];                  // (8,64)
    int tid = threadIdx.x;
    for (int i = tid; i < 512; i += 256) {
        const float* p = in4 + i * 4;
        xs[i] = 0.25f * (p[0] + p[1] + p[2] + p[3]);
    }
    __syncthreads();
    for (int o = tid; o < 8 * 640; o += 256) {
        int i = o % 640;
        int b = o / 640;
        float s = fcb[i];
        const float* wrow = fcw + i * 64;
        const float* xb   = xs + b * 64;
#pragma unroll 8
        for (int c = 0; c < 64; ++c) s += xb[c] * wrow[c];
        R[o] = s;
    }
}

// ---------- out = feat + sum_k R_k * basis_k(h,w), basis analytic ----------
__global__ __launch_bounds__(256) void final_add_k(const float* __restrict__ feat,
                                                   const float* __restrict__ R,
                                                   float* __restrict__ out) {
    int blk   = blockIdx.x;
    int hhalf = blk & 1;
    int t     = blk >> 1;
    int c     = t & 63;
    int b     = t >> 6;
    int w     = threadIdx.x;

    const float* Rp = R + (b * 640 + c * 10);
    float r0 = Rp[0], r1 = Rp[1], r2 = Rp[2], r3 = Rp[3], r4 = Rp[4];
    float r5 = Rp[5], r6 = Rp[6], r7 = Rp[7], r8 = Rp[8], r9 = Rp[9];

    float xw  = (float)(w + 1) * (1.0f / 256.0f);
    float Lw  = __builtin_amdgcn_logf(xw);       // log2(x_w)
    float ejw = (float)(255 - w);

    size_t base = (((size_t)(b * 64 + c) * 256) + (size_t)hhalf * 128) * 256 + w;
    const float* fp = feat + base;
    float*       op = out + base;

#pragma unroll 4
    for (int hh = 0; hh < 128; ++hh) {
        int h = hhalf * 128 + hh;
        float xi = (float)(h + 1) * (1.0f / 256.0f);
        float Lh = __builtin_amdgcn_logf(xi);
        float a  = __builtin_amdgcn_exp2f(ejw * Lh);               // x_h^(255-w)
        float bb = __builtin_amdgcn_exp2f((float)(255 - h) * Lw);  // x_w^(255-h)
        float mask = (r9 + r3)
                   + bb * (r8 + bb * (r7 + bb * r6))
                   + a * ((r5 + bb * (r4 + bb * r3))
                          + a * (r2 + bb * r1 + a * r0));
        op[(size_t)hh * 256] = fp[(size_t)hh * 256] + mask;
    }
}

extern "C" void kernel_launch(void* const* d_in, const int* in_sizes, int n_in,
                              void* d_out, int out_size, void* d_ws, size_t ws_size,
                              hipStream_t stream) {
    const float* feat = (const float*)d_in[0];
    const float* w1   = (const float*)d_in[1];
    const float* b1   = (const float*)d_in[2];
    const float* w2   = (const float*)d_in[3];
    const float* b2   = (const float*)d_in[4];
    const float* w3   = (const float*)d_in[5];
    const float* b3   = (const float*)d_in[6];
    const float* w4   = (const float*)d_in[7];
    const float* b4   = (const float*)d_in[8];
    const float* fcw  = (const float*)d_in[9];
    const float* fcb  = (const float*)d_in[10];
    float* out = (float*)d_out;

    // workspace layout (floats)
    float* ws    = (float*)d_ws;
    float* wt1   = ws;              // 36864 (reused as wpk, bf16)
    float* wt2   = wt1 + 36864;
    float* wt3   = wt2 + 36864;
    float* wt4   = wt3 + 36864;
    float* out1  = wt4 + 36864;     // 8388608
    float* pool1 = out1 + 8388608;  // 2097152
    float* out2  = pool1 + 2097152; // 524288
    float* pool2 = out2 + 524288;   // 131072
    float* out3  = pool2 + 131072;  // 32768
    float* pool3 = out3 + 32768;    // 8192
    float* out4  = pool3 + 8192;    // 2048
    float* Rm    = out4 + 2048;     // 5120
    unsigned short* wpk = (unsigned short*)wt1;

    // weight prep
    wpack_k<<<144, 256, 0, stream>>>(w1, wpk);
    wtrans_k<<<144, 256, 0, stream>>>(w2, wt2);
    wtrans_k<<<144, 256, 0, stream>>>(w3, wt3);
    wtrans_k<<<144, 256, 0, stream>>>(w4, wt4);

    // conv1 via MFMA: 256 -> 128
    conv1_mfma<<<1024, 256, 0, stream>>>(feat, wpk, b1, out1);
    // pool1: 128 -> 64
    maxpool_k<64, 64><<<(2097152 + 255) / 256, 256, 0, stream>>>(out1, pool1, 2097152);
    // conv2: 64 -> 32
    conv_s2<64, 64, 32, 32, 8><<<256, 256, 0, stream>>>(pool1, wt2, b2, out2);
    // pool2: 32 -> 16
    maxpool_k<16, 16><<<(131072 + 255) / 256, 256, 0, stream>>>(out2, pool2, 131072);
    // conv3: 16 -> 8
    conv_s2<16, 16, 8, 8, 8><<<16, 256, 0, stream>>>(pool2, wt3, b3, out3);
    // pool3: 8 -> 4
    maxpool_k<4, 4><<<(8192 + 255) / 256, 256, 0, stream>>>(out3, pool3, 8192);
    // conv4: 4 -> 2
    conv_s2<4, 4, 2, 2, 2><<<4, 256, 0, stream>>>(pool3, wt4, b4, out4);
    // mean + FC
    meanfc_k<<<1, 256, 0, stream>>>(out4, fcw, fcb, Rm);
    // final: feat + mask
    final_add_k<<<1024, 256, 0, stream>>>(feat, Rm, out);
}

// Round 4
// 202.847 us; speedup vs baseline: 3.1085x; 1.7125x over previous
//
#include <hip/hip_runtime.h>
#include <hip/hip_bf16.h>
#include <cstddef>

#define LEAKY 0.01f

typedef short short8 __attribute__((ext_vector_type(8)));
typedef float f32x4 __attribute__((ext_vector_type(4)));

__device__ inline unsigned short bf16b(float f) {
    __hip_bfloat16 h = __float2bfloat16(f);   // RN
    return __builtin_bit_cast(unsigned short, h);
}
__device__ inline float b2f(unsigned short u) {
    unsigned v = (unsigned)u << 16;
    return __builtin_bit_cast(float, v);
}
constexpr int ilog2c(int x) { return x <= 1 ? 0 : 1 + ilog2c(x / 2); }

// ---------- prepack conv weights into MFMA A-fragment order ----------
// wpk[(((tap*4+mt)*2+ks)*64 + lane)*8 + j] bf16
// A[m=co][k=ci]: co = mt*16 + (lane&15), ci = ks*32 + (lane>>4)*8 + j
__global__ __launch_bounds__(256) void wpack_k(const float* __restrict__ w,
                                               unsigned short* __restrict__ wpk) {
    int idx = blockIdx.x * 256 + threadIdx.x;   // 36864 = 9*4*2*64*8
    int j    = idx & 7;
    int lane = (idx >> 3) & 63;
    int rest = idx >> 9;        // (tap*4+mt)*2+ks
    int ks   = rest & 1;
    int mt   = (rest >> 1) & 3;
    int tap  = rest >> 3;       // 0..8
    int co = mt * 16 + (lane & 15);
    int ci = ks * 32 + (lane >> 4) * 8 + j;
    wpk[idx] = bf16b(w[(co * 64 + ci) * 9 + tap]);
}

// ---------- feat NCHW f32 -> featT NHWC bf16 (LDS tile transpose) ----------
__global__ __launch_bounds__(256) void nhwc_k(const float* __restrict__ feat,
                                              unsigned short* __restrict__ featT) {
    __shared__ unsigned short T[64 * 66];
    int blk = blockIdx.x;                 // (b<<10)|(r<<2)|cb
    int cb = blk & 3, r = (blk >> 2) & 255, b = blk >> 10;
    int t = threadIdx.x, lane = t & 63, wv = t >> 6;
    const float* src = feat + (((size_t)(b * 64) * 256 + r) * 256 + cb * 64 + lane);
#pragma unroll
    for (int i = 0; i < 16; ++i) {
        int ci = wv * 16 + i;
        T[ci * 66 + lane] = bf16b(src[(size_t)ci * 65536]);
    }
    __syncthreads();
    int col = t & 63, cig = t >> 6;
    unsigned pk[8];
#pragma unroll
    for (int k = 0; k < 8; ++k) {
        unsigned lo = T[(cig * 16 + 2 * k) * 66 + col];
        unsigned hi = T[(cig * 16 + 2 * k + 1) * 66 + col];
        pk[k] = lo | (hi << 16);
    }
    unsigned short* dst = featT +
        ((((size_t)(b * 256) + r) * 256 + cb * 64 + col) * 64 + cig * 16);
    *(uint4*)(dst)     = make_uint4(pk[0], pk[1], pk[2], pk[3]);
    *(uint4*)(dst + 8) = make_uint4(pk[4], pk[5], pk[6], pk[7]);
}

// ---------- conv 3x3 s2 p1 (64ci->64co) on NHWC bf16, direct MFMA ----------
// wave = 32-pixel output strip. A=weights (prepacked), B=pixels (direct
// predicated dwordx4 from featT). No LDS, no barriers.
template<int IH, int OH, int OW, int NB>
__global__ __launch_bounds__(256) void conv_mfma(const unsigned short* __restrict__ inT,
                                                 const unsigned short* __restrict__ wpk,
                                                 const float* __restrict__ bias,
                                                 unsigned short* __restrict__ outT) {
    constexpr int IW = IH;
    constexpr int NSTRIP = OH * OW * 8 / 32;
    constexpr int LOGOW = ilog2c(OW), LOGOH = ilog2c(OH);
    int blk = blockIdx.x;
    if constexpr (NB >= 8 && (NB % 8) == 0) {      // XCD-bijective swizzle
        blk = (blk & 7) * (NB / 8) + (blk >> 3);
    }
    int gw = (blk * 256 + (int)threadIdx.x) >> 6;
    if (gw >= NSTRIP) return;
    int lane = threadIdx.x & 63;
    int n = lane & 15, kg = lane >> 4;
    int p0 = gw * 32;

    int bv[2], ohv[2], owv[2];
#pragma unroll
    for (int nt = 0; nt < 2; ++nt) {
        int p = p0 + nt * 16 + n;
        bv[nt]  = p >> (LOGOH + LOGOW);
        ohv[nt] = (p >> LOGOW) & (OH - 1);
        owv[nt] = p & (OW - 1);
    }
    float4 bias4[4];
#pragma unroll
    for (int mt = 0; mt < 4; ++mt)
        bias4[mt] = *(const float4*)(bias + mt * 16 + kg * 4);

    f32x4 acc[4][2] = {};
#pragma unroll
    for (int dr = 0; dr < 3; ++dr) {
#pragma unroll
        for (int dc = 0; dc < 3; ++dc) {
            int tap = dr * 3 + dc;
            short8 Aw[4][2];
#pragma unroll
            for (int mt = 0; mt < 4; ++mt)
#pragma unroll
                for (int ks = 0; ks < 2; ++ks)
                    Aw[mt][ks] = *(const short8*)(wpk +
                        ((((tap * 4 + mt) * 2 + ks) * 64 + lane) << 3));
            short8 Bx[2][2];
#pragma unroll
            for (int nt = 0; nt < 2; ++nt) {
                int r = 2 * ohv[nt] - 1 + dr;       // in [-1, IH-1]
                int c = 2 * owv[nt] - 1 + dc;       // in [-1, IW-1]
                bool ok = (r >= 0) && (c >= 0);
                long long off = (((long long)bv[nt] * IH + r) * IW + c) * 64 + kg * 8;
#pragma unroll
                for (int ks = 0; ks < 2; ++ks) {
                    short8 z = {0, 0, 0, 0, 0, 0, 0, 0};
                    if (ok) z = *(const short8*)(inT + off + ks * 32);
                    Bx[nt][ks] = z;
                }
            }
#pragma unroll
            for (int ks = 0; ks < 2; ++ks)
#pragma unroll
                for (int nt = 0; nt < 2; ++nt)
#pragma unroll
                    for (int mt = 0; mt < 4; ++mt)
                        acc[mt][nt] = __builtin_amdgcn_mfma_f32_16x16x32_bf16(
                            Aw[mt][ks], Bx[nt][ks], acc[mt][nt], 0, 0, 0);
        }
    }
    // epilogue: bias + leaky -> bf16, 8B stores. D: col=pixel(lane&15),
    // row = co_in_tile = kg*4+reg (+mt*16)
#pragma unroll
    for (int nt = 0; nt < 2; ++nt) {
        size_t pb = ((size_t)(p0 + nt * 16 + n)) * 64;
#pragma unroll
        for (int mt = 0; mt < 4; ++mt) {
            float v0 = acc[mt][nt][0] + bias4[mt].x; v0 = v0 > 0.f ? v0 : LEAKY * v0;
            float v1 = acc[mt][nt][1] + bias4[mt].y; v1 = v1 > 0.f ? v1 : LEAKY * v1;
            float v2 = acc[mt][nt][2] + bias4[mt].z; v2 = v2 > 0.f ? v2 : LEAKY * v2;
            float v3 = acc[mt][nt][3] + bias4[mt].w; v3 = v3 > 0.f ? v3 : LEAKY * v3;
            unsigned lo = bf16b(v0) | ((unsigned)bf16b(v1) << 16);
            unsigned hi = bf16b(v2) | ((unsigned)bf16b(v3) << 16);
            *(uint2*)(outT + pb + mt * 16 + kg * 4) = make_uint2(lo, hi);
        }
    }
}

// ---------- 2x2 max pool s2 on NHWC bf16 ----------
template<int H, int W>   // output dims
__global__ __launch_bounds__(256) void pool_k(const unsigned short* __restrict__ in,
                                              unsigned short* __restrict__ out) {
    constexpr int TOT = 8 * H * W * 8;   // one thread per 8 ci
    int idx = blockIdx.x * 256 + threadIdx.x;
    if (idx >= TOT) return;
    int cig = idx & 7;
    int pix = idx >> 3;
    int x = pix & (W - 1);
    int y = (pix >> ilog2c(W)) & (H - 1);
    int b = pix >> (ilog2c(W) + ilog2c(H));
    const unsigned short* p0 = in +
        (((size_t)(b * 2 * H + 2 * y) * (2 * W)) + 2 * x) * 64 + cig * 8;
    short8 a0 = *(const short8*)(p0);
    short8 a1 = *(const short8*)(p0 + 64);
    short8 a2 = *(const short8*)(p0 + (size_t)2 * W * 64);
    short8 a3 = *(const short8*)(p0 + (size_t)2 * W * 64 + 64);
    short8 r;
#pragma unroll
    for (int j = 0; j < 8; ++j) {
        float m = fmaxf(fmaxf(b2f((unsigned short)a0[j]), b2f((unsigned short)a1[j])),
                        fmaxf(b2f((unsigned short)a2[j]), b2f((unsigned short)a3[j])));
        r[j] = (short)(__builtin_bit_cast(unsigned, m) >> 16);
    }
    *(short8*)(out + (size_t)idx * 8) = r;
}

// ---------- mean(2x2, NHWC bf16) + FC ----------
__global__ __launch_bounds__(256) void meanfc_k(const unsigned short* __restrict__ in4,
                                                const float* __restrict__ fcw,
                                                const float* __restrict__ fcb,
                                                float* __restrict__ R) {
    __shared__ float xs[512];
    int tid = threadIdx.x;
    for (int i = tid; i < 512; i += 256) {
        int b = i >> 6, c = i & 63;
        const unsigned short* p = in4 + b * 256 + c;
        xs[i] = 0.25f * (b2f(p[0]) + b2f(p[64]) + b2f(p[128]) + b2f(p[192]));
    }
    __syncthreads();
    for (int o = tid; o < 5120; o += 256) {
        int i = o % 640, b = o / 640;
        float s = fcb[i];
        const float* wrow = fcw + i * 64;
        const float* xb   = xs + b * 64;
#pragma unroll 8
        for (int c = 0; c < 64; ++c) s += xb[c] * wrow[c];
        R[o] = s;
    }
}

// ---------- out = feat + sum_k R_k * basis_k(h,w), basis analytic ----------
__global__ __launch_bounds__(256) void final_add_k(const float* __restrict__ feat,
                                                   const float* __restrict__ R,
                                                   float* __restrict__ out) {
    int blk   = blockIdx.x;
    int hhalf = blk & 1;
    int t     = blk >> 1;
    int c     = t & 63;
    int b     = t >> 6;
    int w     = threadIdx.x;

    const float* Rp = R + (b * 640 + c * 10);
    float r0 = Rp[0], r1 = Rp[1], r2 = Rp[2], r3 = Rp[3], r4 = Rp[4];
    float r5 = Rp[5], r6 = Rp[6], r7 = Rp[7], r8 = Rp[8], r9 = Rp[9];

    float xw  = (float)(w + 1) * (1.0f / 256.0f);
    float Lw  = __builtin_amdgcn_logf(xw);       // log2(x_w)
    float ejw = (float)(255 - w);

    size_t base = (((size_t)(b * 64 + c) * 256) + (size_t)hhalf * 128) * 256 + w;
    const float* fp = feat + base;
    float*       op = out + base;

#pragma unroll 4
    for (int hh = 0; hh < 128; ++hh) {
        int h = hhalf * 128 + hh;
        float xi = (float)(h + 1) * (1.0f / 256.0f);
        float Lh = __builtin_amdgcn_logf(xi);
        float a  = __builtin_amdgcn_exp2f(ejw * Lh);               // x_h^(255-w)
        float bb = __builtin_amdgcn_exp2f((float)(255 - h) * Lw);  // x_w^(255-h)
        float mask = (r9 + r3)
                   + bb * (r8 + bb * (r7 + bb * r6))
                   + a * ((r5 + bb * (r4 + bb * r3))
                          + a * (r2 + bb * r1 + a * r0));
        op[(size_t)hh * 256] = fp[(size_t)hh * 256] + mask;
    }
}

extern "C" void kernel_launch(void* const* d_in, const int* in_sizes, int n_in,
                              void* d_out, int out_size, void* d_ws, size_t ws_size,
                              hipStream_t stream) {
    const float* feat = (const float*)d_in[0];
    const float* w1   = (const float*)d_in[1];
    const float* b1   = (const float*)d_in[2];
    const float* w2   = (const float*)d_in[3];
    const float* b2   = (const float*)d_in[4];
    const float* w3   = (const float*)d_in[5];
    const float* b3   = (const float*)d_in[6];
    const float* w4   = (const float*)d_in[7];
    const float* b4   = (const float*)d_in[8];
    const float* fcw  = (const float*)d_in[9];
    const float* fcb  = (const float*)d_in[10];
    float* out = (float*)d_out;

    // ws layout (ushort units); total ~22.7 MB
    unsigned short* wsu    = (unsigned short*)d_ws;
    unsigned short* wpk1   = wsu;                        // 36864
    unsigned short* wpk2   = wpk1 + 36864;
    unsigned short* wpk3   = wpk2 + 36864;
    unsigned short* wpk4   = wpk3 + 36864;
    unsigned short* out1T  = wpk4 + 36864;               // 8*128*128*64 = 8388608
    unsigned short* pool1T = out1T + 8388608;            // 2097152
    unsigned short* out2T  = pool1T + 2097152;           // 524288
    unsigned short* pool2T = out2T + 524288;             // 131072
    unsigned short* out3T  = pool2T + 131072;            // 32768
    unsigned short* pool3T = out3T + 32768;              // 8192
    unsigned short* out4T  = pool3T + 8192;              // 2048
    float*          Rm     = (float*)(out4T + 2048);     // 5120 floats
    // featT (NHWC bf16, 67MB) lives in d_out; final_add overwrites all of d_out
    unsigned short* featT  = (unsigned short*)d_out;

    // weight prep
    wpack_k<<<144, 256, 0, stream>>>(w1, wpk1);
    wpack_k<<<144, 256, 0, stream>>>(w2, wpk2);
    wpack_k<<<144, 256, 0, stream>>>(w3, wpk3);
    wpack_k<<<144, 256, 0, stream>>>(w4, wpk4);

    // layout pass: feat -> NHWC bf16
    nhwc_k<<<8192, 256, 0, stream>>>(feat, featT);

    // conv1: 256 -> 128 (4096 strips, 1024 blocks)
    conv_mfma<256, 128, 128, 1024><<<1024, 256, 0, stream>>>(featT, wpk1, b1, out1T);
    pool_k<64, 64><<<1024, 256, 0, stream>>>(out1T, pool1T);
    // conv2: 64 -> 32 (256 strips, 64 blocks)
    conv_mfma<64, 32, 32, 64><<<64, 256, 0, stream>>>(pool1T, wpk2, b2, out2T);
    pool_k<16, 16><<<64, 256, 0, stream>>>(out2T, pool2T);
    // conv3: 16 -> 8 (16 strips, 4 blocks)
    conv_mfma<16, 8, 8, 4><<<4, 256, 0, stream>>>(pool2T, wpk3, b3, out3T);
    pool_k<4, 4><<<4, 256, 0, stream>>>(out3T, pool3T);
    // conv4: 4 -> 2 (1 strip, 1 block)
    conv_mfma<4, 2, 2, 1><<<1, 256, 0, stream>>>(pool3T, wpk4, b4, out4T);
    // mean + FC
    meanfc_k<<<1, 256, 0, stream>>>(out4T, fcw, fcb, Rm);
    // final: feat + mask (overwrites featT scratch)
    final_add_k<<<1024, 256, 0, stream>>>(feat, Rm, out);
}